// Round 1
// baseline (2552.752 us; speedup 1.0000x reference)
//
#include <hip/hip_runtime.h>

typedef unsigned long long u64;

#define NA 50000
#define NE 400000
#define DF 128
#define HID 64
#define NMOL 256
#define NOUT 32
#define NSTEP 3

// ---------------- weight transposes / rearrangement ----------------
// WpT[t][j][d]: column-major fused first-layer weight. Col j<64 -> Win[t][d][j]
// (dst half), col j>=64 -> Win[t][128+d][j-64] (src half).
// WhT[t][j][k] = Wh[t][k][j];  WoT[t][j][k] = Wout[t][k][j].
__global__ void prep_weights(const float* __restrict__ Win,
                             const float* __restrict__ Wh,
                             const float* __restrict__ Wout,
                             float* __restrict__ WpT,
                             float* __restrict__ WhT,
                             float* __restrict__ WoT) {
  int g = blockIdx.x * 256 + threadIdx.x;
  if (g < 3 * 128 * 128) {
    int t = g / 16384, r = g % 16384;
    int j = r >> 7, d = r & 127;
    float v = (j < 64) ? Win[t * 16384 + d * 64 + j]
                       : Win[t * 16384 + (128 + d) * 64 + (j - 64)];
    WpT[g] = v;
  }
  int g2 = g - 3 * 128 * 128;
  if (g2 >= 0 && g2 < 3 * 64 * 64) {
    int t = g2 / 4096, r = g2 % 4096;
    int j = r >> 6, k = r & 63;
    WhT[g2] = Wh[t * 4096 + k * 64 + j];
  }
  int g3 = g2 - 3 * 64 * 64;
  if (g3 >= 0 && g3 < 3 * 128 * 64) {
    int t = g3 / 8192, r = g3 % 8192;
    int j = r >> 6, k = r & 63;
    WoT[g3] = Wout[t * 8192 + k * 128 + j];
  }
}

// ---------------- CSR build (sort edges by dst) ----------------
__global__ void count_edges(const int* __restrict__ dst, int* __restrict__ counts) {
  int e = blockIdx.x * 256 + threadIdx.x;
  if (e < NE) atomicAdd(&counts[dst[e]], 1);
}

// single block, 1024 threads: 3-phase scan (seg-sum, Hillis-Steele, seg-write)
__global__ void scan_counts(const int* __restrict__ counts, int* __restrict__ row_ptr) {
  __shared__ int part[1024];
  int t = threadIdx.x;
  const int L = (NA + 1023) / 1024;  // 49
  int begin = t * L;
  int end = begin + L; if (end > NA) end = NA;
  int s = 0;
  for (int i = begin; i < end; i++) s += counts[i];
  part[t] = s;
  __syncthreads();
  for (int off = 1; off < 1024; off <<= 1) {
    int x = (t >= off) ? part[t - off] : 0;
    __syncthreads();
    part[t] += x;
    __syncthreads();
  }
  int run = (t == 0) ? 0 : part[t - 1];
  if (t == 0) row_ptr[0] = 0;
  for (int i = begin; i < end; i++) {
    run += counts[i];
    row_ptr[i + 1] = run;
  }
}

__global__ void fill_edges(const int* __restrict__ src, const int* __restrict__ dst,
                           const int* __restrict__ row_ptr, int* __restrict__ cursor,
                           int* __restrict__ dst_s, int* __restrict__ src_s) {
  int e = blockIdx.x * 256 + threadIdx.x;
  if (e < NE) {
    int d = dst[e];
    int pos = row_ptr[d] + atomicAdd(&cursor[d], 1);
    dst_s[pos] = d;
    src_s[pos] = src[e];
  }
}

// ---------------- per-node projection: PQ = s @ W' [NA,128] ----------------
// thread = node; s row in VGPRs; W'T rows are thread-uniform -> scalar loads.
__global__ __launch_bounds__(256) void node_proj(const float* __restrict__ s_in,
                                                 const float* __restrict__ WpT_t,
                                                 float* __restrict__ PQ) {
  int n = blockIdx.x * 256 + threadIdx.x;
  if (n >= NA) return;
  float sr[DF];
  const float4* p = (const float4*)(s_in + (u64)n * DF);
#pragma unroll
  for (int q = 0; q < DF / 4; q++) {
    float4 v = p[q];
    sr[4 * q] = v.x; sr[4 * q + 1] = v.y; sr[4 * q + 2] = v.z; sr[4 * q + 3] = v.w;
  }
  float* out = PQ + (u64)n * DF;
#pragma unroll 1
  for (int j = 0; j < DF; j++) {
    const float* w = WpT_t + j * DF;
    float a0 = 0.f, a1 = 0.f, a2 = 0.f, a3 = 0.f;
#pragma unroll
    for (int d = 0; d < DF; d += 4) {
      a0 = fmaf(sr[d + 0], w[d + 0], a0);
      a1 = fmaf(sr[d + 1], w[d + 1], a1);
      a2 = fmaf(sr[d + 2], w[d + 2], a2);
      a3 = fmaf(sr[d + 3], w[d + 3], a3);
    }
    out[j] = (a0 + a1) + (a2 + a3);
  }
}

// ---------------- fused edge MLP + segment-sum into s_next ----------------
// thread = sorted edge. h1/h2 in VGPRs, transposed weights via scalar loads.
// Aggregation: per-wave LDS slot table over the wave's (sorted, contiguous)
// dst range; flush one global atomic per live slot per column.
__global__ __launch_bounds__(256) void edge_mlp(
    const float* __restrict__ PQ,
    const float* __restrict__ WhT_t, const float* __restrict__ WoT_t,
    const float* __restrict__ b_in_t, const float* __restrict__ b_h_t,
    const float* __restrict__ b_out_t,
    const int* __restrict__ dst_s, const int* __restrict__ src_s,
    float* __restrict__ s_next) {
  __shared__ float tbl[4][64];
  int tid = threadIdx.x;
  int lane = tid & 63, wv = tid >> 6;
  long long pos = (long long)blockIdx.x * 256 + tid;
  int cpos = (pos < NE) ? (int)pos : (NE - 1);
  float msk = (pos < NE) ? 1.f : 0.f;
  int d = dst_s[cpos];
  int sr = src_s[cpos];
  int d0 = __builtin_amdgcn_readfirstlane(d);  // wave's first dst (sorted => min)
  int slot = d - d0;                           // >= 0 by sortedness
  bool inl = slot < 64;

  // h1 = relu(P[d] + Q[sr] + b_in)
  float h1[HID];
  const float4* pd = (const float4*)(PQ + (u64)d * DF);
  const float4* ps = (const float4*)(PQ + (u64)sr * DF + HID);
#pragma unroll
  for (int q = 0; q < 16; q++) {
    float4 a = pd[q], b = ps[q];
    h1[4 * q + 0] = fmaxf(a.x + b.x + b_in_t[4 * q + 0], 0.f);
    h1[4 * q + 1] = fmaxf(a.y + b.y + b_in_t[4 * q + 1], 0.f);
    h1[4 * q + 2] = fmaxf(a.z + b.z + b_in_t[4 * q + 2], 0.f);
    h1[4 * q + 3] = fmaxf(a.w + b.w + b_in_t[4 * q + 3], 0.f);
  }

  // h2 = relu(h1 @ Wh + b_h)
  float h2[HID];
#pragma unroll
  for (int j = 0; j < HID; j++) {
    const float* w = WhT_t + j * HID;
    float a0 = 0.f, a1 = 0.f, a2 = 0.f, a3 = 0.f;
#pragma unroll
    for (int k = 0; k < HID; k += 4) {
      a0 = fmaf(h1[k + 0], w[k + 0], a0);
      a1 = fmaf(h1[k + 1], w[k + 1], a1);
      a2 = fmaf(h1[k + 2], w[k + 2], a2);
      a3 = fmaf(h1[k + 3], w[k + 3], a3);
    }
    h2[j] = fmaxf((a0 + a1) + (a2 + a3) + b_h_t[j], 0.f);
  }

  // m_j = relu(h2 @ Wout + b_out), aggregated by dst
  float* mt = tbl[wv];
#pragma unroll 1
  for (int j = 0; j < DF; j++) {
    const float* w = WoT_t + j * HID;
    float a0 = 0.f, a1 = 0.f, a2 = 0.f, a3 = 0.f;
#pragma unroll
    for (int k = 0; k < HID; k += 4) {
      a0 = fmaf(h2[k + 0], w[k + 0], a0);
      a1 = fmaf(h2[k + 1], w[k + 1], a1);
      a2 = fmaf(h2[k + 2], w[k + 2], a2);
      a3 = fmaf(h2[k + 3], w[k + 3], a3);
    }
    float m = fmaxf((a0 + a1) + (a2 + a3) + b_out_t[j], 0.f) * msk;

    mt[lane] = 0.f;                       // zero all 64 slots
    __builtin_amdgcn_wave_barrier();
    if (inl) {
      if (m != 0.f) atomicAdd(&mt[slot], m);          // ds_add_f32
    } else if (m != 0.f) {
      atomicAdd(&s_next[(u64)d * DF + j], m);         // rare: range overflow
    }
    __builtin_amdgcn_wave_barrier();
    float v = mt[lane];
    __builtin_amdgcn_wave_barrier();
    if (v != 0.f) atomicAdd(&s_next[(u64)(d0 + lane) * DF + j], v);
  }
}

// ---------------- molecule aggregation ----------------
__global__ void mol_agg(const float* __restrict__ s_fin, const int* __restrict__ mol_ids,
                        float* __restrict__ mol_repr) {
  long long g = (long long)blockIdx.x * 256 + threadIdx.x;
  if (g >= (long long)NA * DF) return;
  int a = (int)(g >> 7), j = (int)(g & 127);
  float v = s_fin[g];
  if (v != 0.f) atomicAdd(&mol_repr[(u64)mol_ids[a] * DF + j], v);
}

// ---------------- final tiny MLP per molecule ----------------
__global__ void final_mlp(const float* __restrict__ mol_repr,
                          const float* __restrict__ fc1_w, const float* __restrict__ fc1_b,
                          const float* __restrict__ fc2_w, const float* __restrict__ fc2_b,
                          const float* __restrict__ out_w, const float* __restrict__ out_b,
                          float* __restrict__ out) {
  int m = blockIdx.x, j = threadIdx.x;
  __shared__ float h1s[64], h2s[64];
  const float* mr = mol_repr + (u64)m * DF;  // uniform -> scalar loads
  float acc = fc1_b[j];
  for (int d = 0; d < DF; d++) acc = fmaf(mr[d], fc1_w[d * 64 + j], acc);
  h1s[j] = fmaxf(acc, 0.f);
  __syncthreads();
  acc = fc2_b[j];
  for (int k = 0; k < 64; k++) acc = fmaf(h1s[k], fc2_w[k * 64 + j], acc);
  h2s[j] = fmaxf(acc, 0.f);
  __syncthreads();
  if (j < NOUT) {
    acc = out_b[j];
    for (int k = 0; k < 64; k++) acc = fmaf(h2s[k], out_w[k * NOUT + j], acc);
    out[(u64)m * NOUT + j] = acc;
  }
}

extern "C" void kernel_launch(void* const* d_in, const int* in_sizes, int n_in,
                              void* d_out, int out_size, void* d_ws, size_t ws_size,
                              hipStream_t stream) {
  const float* states = (const float*)d_in[0];
  const float* Win    = (const float*)d_in[1];
  const float* b_in   = (const float*)d_in[2];
  const float* Wh     = (const float*)d_in[3];
  const float* b_h    = (const float*)d_in[4];
  const float* Wout   = (const float*)d_in[5];
  const float* b_out  = (const float*)d_in[6];
  const float* fc1_w  = (const float*)d_in[7];
  const float* fc1_b  = (const float*)d_in[8];
  const float* fc2_w  = (const float*)d_in[9];
  const float* fc2_b  = (const float*)d_in[10];
  const float* out_w  = (const float*)d_in[11];
  const float* out_b  = (const float*)d_in[12];
  const int* src      = (const int*)d_in[13];
  const int* dst      = (const int*)d_in[14];
  const int* mol_ids  = (const int*)d_in[15];

  char* ws = (char*)d_ws;
  u64 o = 0;
  auto alloc = [&](u64 bytes) {
    void* p = ws + o;
    o += (bytes + 255) & ~255ull;
    return p;
  };
  float* PQ   = (float*)alloc((u64)NA * DF * 4);
  float* sA   = (float*)alloc((u64)NA * DF * 4);
  float* sB   = (float*)alloc((u64)NA * DF * 4);
  float* WpT  = (float*)alloc(3 * 128 * 128 * 4);
  float* WhT  = (float*)alloc(3 * 64 * 64 * 4);
  float* WoT  = (float*)alloc(3 * 128 * 64 * 4);
  float* molr = (float*)alloc((u64)NMOL * DF * 4);
  int* counts = (int*)alloc((u64)NA * 4);
  int* row_ptr= (int*)alloc((u64)(NA + 1) * 4);
  int* cursor = (int*)alloc((u64)NA * 4);
  int* dst_s  = (int*)alloc((u64)NE * 4);
  int* src_s  = (int*)alloc((u64)NE * 4);
  (void)ws_size; (void)in_sizes; (void)n_in; (void)out_size;

  hipMemsetAsync(counts, 0, (u64)NA * 4, stream);
  hipMemsetAsync(cursor, 0, (u64)NA * 4, stream);
  hipMemsetAsync(molr, 0, (u64)NMOL * DF * 4, stream);

  prep_weights<<<336, 256, 0, stream>>>(Win, Wh, Wout, WpT, WhT, WoT);
  count_edges<<<(NE + 255) / 256, 256, 0, stream>>>(dst, counts);
  scan_counts<<<1, 1024, 0, stream>>>(counts, row_ptr);
  fill_edges<<<(NE + 255) / 256, 256, 0, stream>>>(src, dst, row_ptr, cursor, dst_s, src_s);

  const float* scur = states;
  float* snxt = sA;
  for (int t = 0; t < NSTEP; t++) {
    node_proj<<<(NA + 255) / 256, 256, 0, stream>>>(scur, WpT + t * 16384, PQ);
    hipMemsetAsync(snxt, 0, (u64)NA * DF * 4, stream);
    edge_mlp<<<(NE + 255) / 256, 256, 0, stream>>>(
        PQ, WhT + t * 4096, WoT + t * 8192,
        b_in + t * 64, b_h + t * 64, b_out + t * 128, dst_s, src_s, snxt);
    scur = snxt;
    snxt = (snxt == sA) ? sB : sA;
  }
  mol_agg<<<(int)(((u64)NA * DF + 255) / 256), 256, 0, stream>>>(scur, mol_ids, molr);
  final_mlp<<<NMOL, 64, 0, stream>>>(molr, fc1_w, fc1_b, fc2_w, fc2_b, out_w, out_b,
                                     (float*)d_out);
}

// Round 3
// 660.374 us; speedup vs baseline: 3.8656x; 3.8656x over previous
//
#include <hip/hip_runtime.h>

typedef unsigned long long u64;
typedef unsigned short ushort_t;

#define NA 50000
#define NE 400000
#define DF 128
#define HID 64
#define NMOL 256
#define NOUT 32
#define NSTEP 3

typedef __attribute__((ext_vector_type(8))) short short8;
typedef __attribute__((ext_vector_type(4))) float f32x4;

static __device__ __forceinline__ ushort_t f2bf(float f) {
  union { float f; unsigned u; } v; v.f = f;
  unsigned r = v.u + 0x7fffu + ((v.u >> 16) & 1u);
  return (ushort_t)(r >> 16);
}

// ---------------- pack weights into MFMA B-fragment order (bf16) -----------
// B-frag for mfma_f32_16x16x32_bf16: lane l holds B[k=(l>>4)*8+j][n=l&15].
__global__ void pack_weights(const float* __restrict__ Win,
                             const float* __restrict__ Wh,
                             const float* __restrict__ Wout,
                             ushort_t* __restrict__ WpB,
                             ushort_t* __restrict__ WhB,
                             ushort_t* __restrict__ WoB) {
  int g = blockIdx.x * 256 + threadIdx.x;
  if (g < 3 * 16384) {
    int tt = g / 16384, r = g % 16384;
    int j = r & 7, lane = (r >> 3) & 63, f = r >> 9;
    int kc = f & 3, nt = f >> 2;
    int k = kc * 32 + (lane >> 4) * 8 + j;
    int n = nt * 16 + (lane & 15);
    float v = (n < 64) ? Win[tt * 16384 + k * 64 + n]
                       : Win[tt * 16384 + (128 + k) * 64 + (n - 64)];
    WpB[g] = f2bf(v);
  }
  int g2 = g - 3 * 16384;
  if (g2 >= 0 && g2 < 3 * 4096) {
    int tt = g2 / 4096, r = g2 % 4096;
    int j = r & 7, lane = (r >> 3) & 63, f = r >> 9;
    int kc = f & 1, nt = f >> 1;
    int k = kc * 32 + (lane >> 4) * 8 + j;
    int n = nt * 16 + (lane & 15);
    WhB[g2] = f2bf(Wh[tt * 4096 + k * 64 + n]);
  }
  int g3 = g2 - 3 * 4096;
  if (g3 >= 0 && g3 < 3 * 8192) {
    int tt = g3 / 8192, r = g3 % 8192;
    int j = r & 7, lane = (r >> 3) & 63, f = r >> 9;
    int kc = f & 1, nt = f >> 1;
    int k = kc * 32 + (lane >> 4) * 8 + j;
    int n = nt * 16 + (lane & 15);
    WoB[g3] = f2bf(Wout[tt * 8192 + k * 128 + n]);
  }
}

// ---------------- CSR build (sort edges by dst) ----------------
__global__ void count_edges(const int* __restrict__ dst, int* __restrict__ counts) {
  int e = blockIdx.x * 256 + threadIdx.x;
  if (e < NE) atomicAdd(&counts[dst[e]], 1);
}

__global__ void scan_counts(const int* __restrict__ counts, int* __restrict__ row_ptr) {
  __shared__ int part[1024];
  int t = threadIdx.x;
  const int L = (NA + 1023) / 1024;  // 49
  int begin = t * L;
  int end = begin + L; if (end > NA) end = NA;
  int s = 0;
  for (int i = begin; i < end; i++) s += counts[i];
  part[t] = s;
  __syncthreads();
  for (int off = 1; off < 1024; off <<= 1) {
    int x = (t >= off) ? part[t - off] : 0;
    __syncthreads();
    part[t] += x;
    __syncthreads();
  }
  int run = (t == 0) ? 0 : part[t - 1];
  if (t == 0) row_ptr[0] = 0;
  for (int i = begin; i < end; i++) {
    run += counts[i];
    row_ptr[i + 1] = run;
  }
}

__global__ void fill_edges(const int* __restrict__ src, const int* __restrict__ dst,
                           const int* __restrict__ row_ptr, int* __restrict__ cursor,
                           int* __restrict__ dst_s, int* __restrict__ src_s) {
  int e = blockIdx.x * 256 + threadIdx.x;
  if (e < NE) {
    int d = dst[e];
    int pos = row_ptr[d] + atomicAdd(&cursor[d], 1);
    dst_s[pos] = d;
    src_s[pos] = src[e];
  }
}

// ---------------- node projection: PQ = s @ W'  (MFMA bf16, LDS-free) ------
// 64 nodes / workgroup (4 waves x 16). Lane builds its own A-frag from global.
__global__ __launch_bounds__(256) void node_proj(const float* __restrict__ s_in,
                                                 const ushort_t* __restrict__ WpB,
                                                 float* __restrict__ PQ) {
  const int t = threadIdx.x;
  const int lane = t & 63, wv = t >> 6, quad = lane >> 4, l15 = lane & 15;
  const int n0 = blockIdx.x * 64 + wv * 16;
  int n = n0 + l15; if (n >= NA) n = NA - 1;
  union { short8 v; ushort_t u[8]; } a[4];
#pragma unroll
  for (int c = 0; c < 4; c++) {
    const float* p = s_in + (u64)n * 128 + c * 32 + quad * 8;
    float4 f0 = *(const float4*)(p);
    float4 f1 = *(const float4*)(p + 4);
    a[c].u[0] = f2bf(f0.x); a[c].u[1] = f2bf(f0.y);
    a[c].u[2] = f2bf(f0.z); a[c].u[3] = f2bf(f0.w);
    a[c].u[4] = f2bf(f1.x); a[c].u[5] = f2bf(f1.y);
    a[c].u[6] = f2bf(f1.z); a[c].u[7] = f2bf(f1.w);
  }
#pragma unroll
  for (int nt = 0; nt < 8; nt++) {
    f32x4 acc = {0.f, 0.f, 0.f, 0.f};
#pragma unroll
    for (int c = 0; c < 4; c++) {
      short8 b = *(const short8*)&WpB[((nt * 4 + c) * 64 + lane) * 8];
      acc = __builtin_amdgcn_mfma_f32_16x16x32_bf16(a[c].v, b, acc, 0, 0, 0);
    }
#pragma unroll
    for (int r = 0; r < 4; r++) {
      int nn = n0 + quad * 4 + r;
      if (nn < NA) PQ[(u64)nn * 128 + nt * 16 + l15] = acc[r];
    }
  }
}

// ------------- fused edge MLP (MFMA) + register segmented aggregation ------
// 128 edges / workgroup (4 waves x 2 tiles of 16 edges).
__global__ __launch_bounds__(256) void edge_mlp(
    const float* __restrict__ PQ,
    const ushort_t* __restrict__ WhB, const ushort_t* __restrict__ WoB,
    const float* __restrict__ b_in, const float* __restrict__ b_h,
    const float* __restrict__ b_out,
    const int* __restrict__ dst_s, const int* __restrict__ src_s,
    float* __restrict__ s_next) {
  __shared__ int eds[128], ess[128];
  __shared__ ushort_t h2s[4][16 * 72];  // per-wave 16 x 64 bf16, pitch 72
  const int t = threadIdx.x;
  const int lane = t & 63, wv = t >> 6, quad = lane >> 4, l15 = lane & 15;
  const long long e0 = (long long)blockIdx.x * 128;

  if (t < 128) {
    long long e = e0 + t; if (e >= NE) e = NE - 1;
    eds[t] = dst_s[e]; ess[t] = src_s[e];
  }
  float bh[4], bo[8];
#pragma unroll
  for (int nt = 0; nt < 4; nt++) bh[nt] = b_h[nt * 16 + l15];
#pragma unroll
  for (int nt = 0; nt < 8; nt++) bo[nt] = b_out[nt * 16 + l15];
  __syncthreads();

#pragma unroll 1
  for (int i = 0; i < 2; i++) {
    const int ebl = wv * 32 + i * 16;  // block-local tile base
    const int da = eds[ebl + l15], sa = ess[ebl + l15];

    // A-frag of h1 = relu(P[dst] + Q[src] + b_in) built directly in registers
    union { short8 v; ushort_t u[8]; } a1[2];
#pragma unroll
    for (int c = 0; c < 2; c++) {
      const int col = c * 32 + quad * 8;
      float4 p0 = *(const float4*)(PQ + (u64)da * 128 + col);
      float4 p1 = *(const float4*)(PQ + (u64)da * 128 + col + 4);
      float4 q0 = *(const float4*)(PQ + (u64)sa * 128 + 64 + col);
      float4 q1 = *(const float4*)(PQ + (u64)sa * 128 + 64 + col + 4);
      float4 bi0 = *(const float4*)(b_in + col);
      float4 bi1 = *(const float4*)(b_in + col + 4);
      a1[c].u[0] = f2bf(fmaxf(p0.x + q0.x + bi0.x, 0.f));
      a1[c].u[1] = f2bf(fmaxf(p0.y + q0.y + bi0.y, 0.f));
      a1[c].u[2] = f2bf(fmaxf(p0.z + q0.z + bi0.z, 0.f));
      a1[c].u[3] = f2bf(fmaxf(p0.w + q0.w + bi0.w, 0.f));
      a1[c].u[4] = f2bf(fmaxf(p1.x + q1.x + bi1.x, 0.f));
      a1[c].u[5] = f2bf(fmaxf(p1.y + q1.y + bi1.y, 0.f));
      a1[c].u[6] = f2bf(fmaxf(p1.z + q1.z + bi1.z, 0.f));
      a1[c].u[7] = f2bf(fmaxf(p1.w + q1.w + bi1.w, 0.f));
    }

    // h2 = relu(h1 @ Wh + b_h)
    f32x4 acc1[4];
#pragma unroll
    for (int nt = 0; nt < 4; nt++) {
      f32x4 acc = {0.f, 0.f, 0.f, 0.f};
#pragma unroll
      for (int c = 0; c < 2; c++) {
        short8 b = *(const short8*)&WhB[((nt * 2 + c) * 64 + lane) * 8];
        acc = __builtin_amdgcn_mfma_f32_16x16x32_bf16(a1[c].v, b, acc, 0, 0, 0);
      }
      acc1[nt] = acc;
    }
    // D-layout (row=quad*4+r, col=nt*16+l15) -> row-major LDS, barrier, A-frag
#pragma unroll
    for (int nt = 0; nt < 4; nt++)
#pragma unroll
      for (int r = 0; r < 4; r++)
        h2s[wv][(quad * 4 + r) * 72 + nt * 16 + l15] =
            f2bf(fmaxf(acc1[nt][r] + bh[nt], 0.f));
    __syncthreads();

    union { short8 v; ushort_t u[8]; } a2[2];
#pragma unroll
    for (int c = 0; c < 2; c++)
      a2[c].v = *(const short8*)&h2s[wv][l15 * 72 + c * 32 + quad * 8];

    // m = relu(h2 @ Wout + b_out)
    f32x4 acc2[8];
#pragma unroll
    for (int nt = 0; nt < 8; nt++) {
      f32x4 acc = {0.f, 0.f, 0.f, 0.f};
#pragma unroll
      for (int c = 0; c < 2; c++) {
        short8 b = *(const short8*)&WoB[((nt * 2 + c) * 64 + lane) * 8];
        acc = __builtin_amdgcn_mfma_f32_16x16x32_bf16(a2[c].v, b, acc, 0, 0, 0);
      }
      acc2[nt] = acc;
    }

    // register segmented flush: lane owns edges ebl+quad*4+{0..3}, cols nt*16+l15
    {
      long long egbase = e0 + ebl + quad * 4;
      int prev = eds[ebl + quad * 4];
      float run[8];
#pragma unroll
      for (int nt = 0; nt < 8; nt++) run[nt] = 0.f;
#pragma unroll
      for (int r = 0; r < 4; r++) {
        int dc = eds[ebl + quad * 4 + r];
        if (dc != prev) {
#pragma unroll
          for (int nt = 0; nt < 8; nt++) {
            atomicAdd(&s_next[(u64)prev * 128 + nt * 16 + l15], run[nt]);
            run[nt] = 0.f;
          }
          prev = dc;
        }
        if (egbase + r < NE) {
#pragma unroll
          for (int nt = 0; nt < 8; nt++)
            run[nt] += fmaxf(acc2[nt][r] + bo[nt], 0.f);
        }
      }
      if (egbase < NE) {
#pragma unroll
        for (int nt = 0; nt < 8; nt++)
          atomicAdd(&s_next[(u64)prev * 128 + nt * 16 + l15], run[nt]);
      }
    }
    __syncthreads();  // protect h2s reuse across i
  }
}

// ---------------- molecule aggregation ----------------
__global__ void mol_agg(const float* __restrict__ s_fin, const int* __restrict__ mol_ids,
                        float* __restrict__ mol_repr) {
  long long g = (long long)blockIdx.x * 256 + threadIdx.x;
  if (g >= (long long)NA * DF) return;
  int a = (int)(g >> 7), j = (int)(g & 127);
  float v = s_fin[g];
  if (v != 0.f) atomicAdd(&mol_repr[(u64)mol_ids[a] * DF + j], v);
}

// ---------------- final tiny MLP per molecule ----------------
__global__ void final_mlp(const float* __restrict__ mol_repr,
                          const float* __restrict__ fc1_w, const float* __restrict__ fc1_b,
                          const float* __restrict__ fc2_w, const float* __restrict__ fc2_b,
                          const float* __restrict__ out_w, const float* __restrict__ out_b,
                          float* __restrict__ out) {
  int m = blockIdx.x, j = threadIdx.x;
  __shared__ float h1sh[64], h2sh[64];
  const float* mr = mol_repr + (u64)m * DF;
  float acc = fc1_b[j];
  for (int d = 0; d < DF; d++) acc = fmaf(mr[d], fc1_w[d * 64 + j], acc);
  h1sh[j] = fmaxf(acc, 0.f);
  __syncthreads();
  acc = fc2_b[j];
  for (int k = 0; k < 64; k++) acc = fmaf(h1sh[k], fc2_w[k * 64 + j], acc);
  h2sh[j] = fmaxf(acc, 0.f);
  __syncthreads();
  if (j < NOUT) {
    acc = out_b[j];
    for (int k = 0; k < 64; k++) acc = fmaf(h2sh[k], out_w[k * NOUT + j], acc);
    out[(u64)m * NOUT + j] = acc;
  }
}

extern "C" void kernel_launch(void* const* d_in, const int* in_sizes, int n_in,
                              void* d_out, int out_size, void* d_ws, size_t ws_size,
                              hipStream_t stream) {
  const float* states = (const float*)d_in[0];
  const float* Win    = (const float*)d_in[1];
  const float* b_in   = (const float*)d_in[2];
  const float* Wh     = (const float*)d_in[3];
  const float* b_h    = (const float*)d_in[4];
  const float* Wout   = (const float*)d_in[5];
  const float* b_out  = (const float*)d_in[6];
  const float* fc1_w  = (const float*)d_in[7];
  const float* fc1_b  = (const float*)d_in[8];
  const float* fc2_w  = (const float*)d_in[9];
  const float* fc2_b  = (const float*)d_in[10];
  const float* out_w  = (const float*)d_in[11];
  const float* out_b  = (const float*)d_in[12];
  const int* src      = (const int*)d_in[13];
  const int* dst      = (const int*)d_in[14];
  const int* mol_ids  = (const int*)d_in[15];

  char* ws = (char*)d_ws;
  u64 o = 0;
  auto alloc = [&](u64 bytes) {
    void* p = ws + o;
    o += (bytes + 255) & ~255ull;
    return p;
  };
  float* PQ     = (float*)alloc((u64)NA * DF * 4);
  float* sA     = (float*)alloc((u64)NA * DF * 4);
  float* sB     = (float*)alloc((u64)NA * DF * 4);
  ushort_t* WpB = (ushort_t*)alloc(3 * 16384 * 2);
  ushort_t* WhB = (ushort_t*)alloc(3 * 4096 * 2);
  ushort_t* WoB = (ushort_t*)alloc(3 * 8192 * 2);
  float* molr   = (float*)alloc((u64)NMOL * DF * 4);
  int* counts   = (int*)alloc((u64)NA * 4);
  int* row_ptr  = (int*)alloc((u64)(NA + 1) * 4);
  int* cursor   = (int*)alloc((u64)NA * 4);
  int* dst_s    = (int*)alloc((u64)NE * 4);
  int* src_s    = (int*)alloc((u64)NE * 4);
  (void)ws_size; (void)in_sizes; (void)n_in; (void)out_size;

  hipMemsetAsync(counts, 0, (u64)NA * 4, stream);
  hipMemsetAsync(cursor, 0, (u64)NA * 4, stream);
  hipMemsetAsync(molr, 0, (u64)NMOL * DF * 4, stream);

  pack_weights<<<336, 256, 0, stream>>>(Win, Wh, Wout, WpB, WhB, WoB);
  count_edges<<<(NE + 255) / 256, 256, 0, stream>>>(dst, counts);
  scan_counts<<<1, 1024, 0, stream>>>(counts, row_ptr);
  fill_edges<<<(NE + 255) / 256, 256, 0, stream>>>(src, dst, row_ptr, cursor, dst_s, src_s);

  const float* scur = states;
  float* snxt = sA;
  for (int t = 0; t < NSTEP; t++) {
    node_proj<<<(NA + 63) / 64, 256, 0, stream>>>(scur, WpB + t * 16384, PQ);
    hipMemsetAsync(snxt, 0, (u64)NA * DF * 4, stream);
    edge_mlp<<<(NE + 127) / 128, 256, 0, stream>>>(
        PQ, WhB + t * 4096, WoB + t * 8192,
        b_in + t * 64, b_h + t * 64, b_out + t * 128, dst_s, src_s, snxt);
    scur = snxt;
    snxt = (snxt == sA) ? sB : sA;
  }
  mol_agg<<<(int)(((u64)NA * DF + 255) / 256), 256, 0, stream>>>(scur, mol_ids, molr);
  final_mlp<<<NMOL, 64, 0, stream>>>(molr, fc1_w, fc1_b, fc2_w, fc2_b, out_w, out_b,
                                     (float*)d_out);
}

// Round 4
// 607.559 us; speedup vs baseline: 4.2017x; 1.0869x over previous
//
#include <hip/hip_runtime.h>

typedef unsigned long long u64;
typedef unsigned short ushort_t;

#define NA 50000
#define NE 400000
#define DF 128
#define HID 64
#define NMOL 256
#define NOUT 32
#define NSTEP 3

typedef __attribute__((ext_vector_type(8))) short short8;
typedef __attribute__((ext_vector_type(4))) float f32x4;

static __device__ __forceinline__ ushort_t f2bf(float f) {
  union { float f; unsigned u; } v; v.f = f;
  unsigned r = v.u + 0x7fffu + ((v.u >> 16) & 1u);
  return (ushort_t)(r >> 16);
}

// ---------------- pack weights into MFMA B-fragment order (bf16) -----------
// B-frag for mfma_f32_16x16x32_bf16: lane l holds B[k=(l>>4)*8+j][n=l&15].
__global__ void pack_weights(const float* __restrict__ Win,
                             const float* __restrict__ Wh,
                             const float* __restrict__ Wout,
                             ushort_t* __restrict__ WpB,
                             ushort_t* __restrict__ WhB,
                             ushort_t* __restrict__ WoB) {
  int g = blockIdx.x * 256 + threadIdx.x;
  if (g < 3 * 16384) {
    int tt = g / 16384, r = g % 16384;
    int j = r & 7, lane = (r >> 3) & 63, f = r >> 9;
    int kc = f & 3, nt = f >> 2;
    int k = kc * 32 + (lane >> 4) * 8 + j;
    int n = nt * 16 + (lane & 15);
    float v = (n < 64) ? Win[tt * 16384 + k * 64 + n]
                       : Win[tt * 16384 + (128 + k) * 64 + (n - 64)];
    WpB[g] = f2bf(v);
  }
  int g2 = g - 3 * 16384;
  if (g2 >= 0 && g2 < 3 * 4096) {
    int tt = g2 / 4096, r = g2 % 4096;
    int j = r & 7, lane = (r >> 3) & 63, f = r >> 9;
    int kc = f & 1, nt = f >> 1;
    int k = kc * 32 + (lane >> 4) * 8 + j;
    int n = nt * 16 + (lane & 15);
    WhB[g2] = f2bf(Wh[tt * 4096 + k * 64 + n]);
  }
  int g3 = g2 - 3 * 4096;
  if (g3 >= 0 && g3 < 3 * 8192) {
    int tt = g3 / 8192, r = g3 % 8192;
    int j = r & 7, lane = (r >> 3) & 63, f = r >> 9;
    int kc = f & 1, nt = f >> 1;
    int k = kc * 32 + (lane >> 4) * 8 + j;
    int n = nt * 16 + (lane & 15);
    WoB[g3] = f2bf(Wout[tt * 8192 + k * 128 + n]);
  }
}

// ---------------- CSR build (sort edges by dst) ----------------
__global__ void count_edges(const int* __restrict__ dst, int* __restrict__ counts) {
  int e = blockIdx.x * 256 + threadIdx.x;
  if (e < NE) atomicAdd(&counts[dst[e]], 1);
}

// 3-phase parallel scan: per-1024-block inclusive scan, block-offset scan, add
__global__ void scan_phase1(const int* __restrict__ counts, int* __restrict__ tmp,
                            int* __restrict__ blk) {
  __shared__ int sh[1024];
  int t = threadIdx.x;
  int i = blockIdx.x * 1024 + t;
  int v = (i < NA) ? counts[i] : 0;
  sh[t] = v;
  __syncthreads();
  for (int off = 1; off < 1024; off <<= 1) {
    int x = (t >= off) ? sh[t - off] : 0;
    __syncthreads();
    sh[t] += x;
    __syncthreads();
  }
  if (i < NA) tmp[i] = sh[t];
  if (t == 1023) blk[blockIdx.x] = sh[1023];
}

__global__ void scan_phase2(int* __restrict__ blk, int nblk) {
  __shared__ int sh[64];
  int t = threadIdx.x;
  sh[t] = (t < nblk) ? blk[t] : 0;
  __syncthreads();
  if (t == 0) {
    int run = 0;
    for (int k = 0; k < nblk; k++) { int c = sh[k]; sh[k] = run; run += c; }
  }
  __syncthreads();
  if (t < nblk) blk[t] = sh[t];
}

__global__ void scan_phase3(const int* __restrict__ tmp, const int* __restrict__ blk,
                            int* __restrict__ row_ptr) {
  int i = blockIdx.x * 1024 + threadIdx.x;
  if (i < NA) row_ptr[i + 1] = tmp[i] + blk[blockIdx.x];
  if (i == 0 && blockIdx.x == 0) row_ptr[0] = 0;
}

__global__ void fill_edges(const int* __restrict__ src, const int* __restrict__ dst,
                           const int* __restrict__ row_ptr, int* __restrict__ cursor,
                           int* __restrict__ dst_s, int* __restrict__ src_s) {
  int e = blockIdx.x * 256 + threadIdx.x;
  if (e < NE) {
    int d = dst[e];
    int pos = row_ptr[d] + atomicAdd(&cursor[d], 1);
    dst_s[pos] = d;
    src_s[pos] = src[e];
  }
}

// ---------------- node projection: PQ = s @ W'  (MFMA bf16, LDS-free) ------
__global__ __launch_bounds__(256) void node_proj(const float* __restrict__ s_in,
                                                 const ushort_t* __restrict__ WpB,
                                                 float* __restrict__ PQ) {
  const int t = threadIdx.x;
  const int lane = t & 63, wv = t >> 6, quad = lane >> 4, l15 = lane & 15;
  const int n0 = blockIdx.x * 64 + wv * 16;
  int n = n0 + l15; if (n >= NA) n = NA - 1;
  union { short8 v; ushort_t u[8]; } a[4];
#pragma unroll
  for (int c = 0; c < 4; c++) {
    const float* p = s_in + (u64)n * 128 + c * 32 + quad * 8;
    float4 f0 = *(const float4*)(p);
    float4 f1 = *(const float4*)(p + 4);
    a[c].u[0] = f2bf(f0.x); a[c].u[1] = f2bf(f0.y);
    a[c].u[2] = f2bf(f0.z); a[c].u[3] = f2bf(f0.w);
    a[c].u[4] = f2bf(f1.x); a[c].u[5] = f2bf(f1.y);
    a[c].u[6] = f2bf(f1.z); a[c].u[7] = f2bf(f1.w);
  }
#pragma unroll
  for (int nt = 0; nt < 8; nt++) {
    f32x4 acc = {0.f, 0.f, 0.f, 0.f};
#pragma unroll
    for (int c = 0; c < 4; c++) {
      short8 b = *(const short8*)&WpB[((nt * 4 + c) * 64 + lane) * 8];
      acc = __builtin_amdgcn_mfma_f32_16x16x32_bf16(a[c].v, b, acc, 0, 0, 0);
    }
#pragma unroll
    for (int r = 0; r < 4; r++) {
      int nn = n0 + quad * 4 + r;
      if (nn < NA) PQ[(u64)nn * 128 + nt * 16 + l15] = acc[r];
    }
  }
}

// ------------- fused edge MLP (MFMA) + register segmented aggregation ------
// 128 edges / workgroup (4 waves x 2 tiles of 16 edges). No in-loop barriers:
// per-(wave,i) private h2s; atomics stay in flight until kernel end.
__global__ __launch_bounds__(256, 3) void edge_mlp(
    const float* __restrict__ PQ,
    const ushort_t* __restrict__ WhB, const ushort_t* __restrict__ WoB,
    const float* __restrict__ b_in, const float* __restrict__ b_h,
    const float* __restrict__ b_out,
    const int* __restrict__ dst_s, const int* __restrict__ src_s,
    float* __restrict__ s_next) {
  __shared__ int eds[128], ess[128];
  __shared__ ushort_t h2s[8][16 * 72];  // per-(wave,i) 16 x 64 bf16, pitch 72
  const int t = threadIdx.x;
  const int lane = t & 63, wv = t >> 6, quad = lane >> 4, l15 = lane & 15;
  const long long e0 = (long long)blockIdx.x * 128;

  if (t < 128) {
    long long e = e0 + t; if (e >= NE) e = NE - 1;
    eds[t] = dst_s[e]; ess[t] = src_s[e];
  }
  float bh[4], bo[8];
#pragma unroll
  for (int nt = 0; nt < 4; nt++) bh[nt] = b_h[nt * 16 + l15];
#pragma unroll
  for (int nt = 0; nt < 8; nt++) bo[nt] = b_out[nt * 16 + l15];
  __syncthreads();

#pragma unroll
  for (int i = 0; i < 2; i++) {
    const int ebl = wv * 32 + i * 16;  // block-local tile base
    const int da = eds[ebl + l15], sa = ess[ebl + l15];

    // A-frag of h1 = relu(P[dst] + Q[src] + b_in) built directly in registers
    union { short8 v; ushort_t u[8]; } a1[2];
#pragma unroll
    for (int c = 0; c < 2; c++) {
      const int col = c * 32 + quad * 8;
      float4 p0 = *(const float4*)(PQ + (u64)da * 128 + col);
      float4 p1 = *(const float4*)(PQ + (u64)da * 128 + col + 4);
      float4 q0 = *(const float4*)(PQ + (u64)sa * 128 + 64 + col);
      float4 q1 = *(const float4*)(PQ + (u64)sa * 128 + 64 + col + 4);
      float4 bi0 = *(const float4*)(b_in + col);
      float4 bi1 = *(const float4*)(b_in + col + 4);
      a1[c].u[0] = f2bf(fmaxf(p0.x + q0.x + bi0.x, 0.f));
      a1[c].u[1] = f2bf(fmaxf(p0.y + q0.y + bi0.y, 0.f));
      a1[c].u[2] = f2bf(fmaxf(p0.z + q0.z + bi0.z, 0.f));
      a1[c].u[3] = f2bf(fmaxf(p0.w + q0.w + bi0.w, 0.f));
      a1[c].u[4] = f2bf(fmaxf(p1.x + q1.x + bi1.x, 0.f));
      a1[c].u[5] = f2bf(fmaxf(p1.y + q1.y + bi1.y, 0.f));
      a1[c].u[6] = f2bf(fmaxf(p1.z + q1.z + bi1.z, 0.f));
      a1[c].u[7] = f2bf(fmaxf(p1.w + q1.w + bi1.w, 0.f));
    }

    // h2 = relu(h1 @ Wh + b_h)
    f32x4 acc1[4];
#pragma unroll
    for (int nt = 0; nt < 4; nt++) {
      f32x4 acc = {0.f, 0.f, 0.f, 0.f};
#pragma unroll
      for (int c = 0; c < 2; c++) {
        short8 b = *(const short8*)&WhB[((nt * 2 + c) * 64 + lane) * 8];
        acc = __builtin_amdgcn_mfma_f32_16x16x32_bf16(a1[c].v, b, acc, 0, 0, 0);
      }
      acc1[nt] = acc;
    }
    // D-layout (row=quad*4+r, col=nt*16+l15) -> row-major LDS (wave-private,
    // same-wave RAW ordered by compiler lgkmcnt) -> A-frag
    ushort_t* hb = h2s[wv * 2 + i];
#pragma unroll
    for (int nt = 0; nt < 4; nt++)
#pragma unroll
      for (int r = 0; r < 4; r++)
        hb[(quad * 4 + r) * 72 + nt * 16 + l15] =
            f2bf(fmaxf(acc1[nt][r] + bh[nt], 0.f));

    union { short8 v; ushort_t u[8]; } a2[2];
#pragma unroll
    for (int c = 0; c < 2; c++)
      a2[c].v = *(const short8*)&hb[l15 * 72 + c * 32 + quad * 8];

    // m = relu(h2 @ Wout + b_out)
    f32x4 acc2[8];
#pragma unroll
    for (int nt = 0; nt < 8; nt++) {
      f32x4 acc = {0.f, 0.f, 0.f, 0.f};
#pragma unroll
      for (int c = 0; c < 2; c++) {
        short8 b = *(const short8*)&WoB[((nt * 2 + c) * 64 + lane) * 8];
        acc = __builtin_amdgcn_mfma_f32_16x16x32_bf16(a2[c].v, b, acc, 0, 0, 0);
      }
      acc2[nt] = acc;
    }

    // register segmented flush: lane owns edges ebl+quad*4+{0..3}, cols nt*16+l15
    {
      long long egbase = e0 + ebl + quad * 4;
      int prev = eds[ebl + quad * 4];
      float run[8];
#pragma unroll
      for (int nt = 0; nt < 8; nt++) run[nt] = 0.f;
#pragma unroll
      for (int r = 0; r < 4; r++) {
        int dc = eds[ebl + quad * 4 + r];
        if (dc != prev) {
#pragma unroll
          for (int nt = 0; nt < 8; nt++) {
            atomicAdd(&s_next[(u64)prev * 128 + nt * 16 + l15], run[nt]);
            run[nt] = 0.f;
          }
          prev = dc;
        }
        if (egbase + r < NE) {
#pragma unroll
          for (int nt = 0; nt < 8; nt++)
            run[nt] += fmaxf(acc2[nt][r] + bo[nt], 0.f);
        }
      }
      if (egbase < NE) {
#pragma unroll
        for (int nt = 0; nt < 8; nt++)
          atomicAdd(&s_next[(u64)prev * 128 + nt * 16 + l15], run[nt]);
      }
    }
  }
}

// ---------------- molecule aggregation ----------------
__global__ void mol_agg(const float* __restrict__ s_fin, const int* __restrict__ mol_ids,
                        float* __restrict__ mol_repr) {
  long long g = (long long)blockIdx.x * 256 + threadIdx.x;
  if (g >= (long long)NA * DF) return;
  int a = (int)(g >> 7), j = (int)(g & 127);
  float v = s_fin[g];
  if (v != 0.f) atomicAdd(&mol_repr[(u64)mol_ids[a] * DF + j], v);
}

// ---------------- final tiny MLP per molecule ----------------
__global__ void final_mlp(const float* __restrict__ mol_repr,
                          const float* __restrict__ fc1_w, const float* __restrict__ fc1_b,
                          const float* __restrict__ fc2_w, const float* __restrict__ fc2_b,
                          const float* __restrict__ out_w, const float* __restrict__ out_b,
                          float* __restrict__ out) {
  int m = blockIdx.x, j = threadIdx.x;
  __shared__ float h1sh[64], h2sh[64];
  const float* mr = mol_repr + (u64)m * DF;
  float acc = fc1_b[j];
  for (int d = 0; d < DF; d++) acc = fmaf(mr[d], fc1_w[d * 64 + j], acc);
  h1sh[j] = fmaxf(acc, 0.f);
  __syncthreads();
  acc = fc2_b[j];
  for (int k = 0; k < 64; k++) acc = fmaf(h1sh[k], fc2_w[k * 64 + j], acc);
  h2sh[j] = fmaxf(acc, 0.f);
  __syncthreads();
  if (j < NOUT) {
    acc = out_b[j];
    for (int k = 0; k < 64; k++) acc = fmaf(h2sh[k], out_w[k * NOUT + j], acc);
    out[(u64)m * NOUT + j] = acc;
  }
}

extern "C" void kernel_launch(void* const* d_in, const int* in_sizes, int n_in,
                              void* d_out, int out_size, void* d_ws, size_t ws_size,
                              hipStream_t stream) {
  const float* states = (const float*)d_in[0];
  const float* Win    = (const float*)d_in[1];
  const float* b_in   = (const float*)d_in[2];
  const float* Wh     = (const float*)d_in[3];
  const float* b_h    = (const float*)d_in[4];
  const float* Wout   = (const float*)d_in[5];
  const float* b_out  = (const float*)d_in[6];
  const float* fc1_w  = (const float*)d_in[7];
  const float* fc1_b  = (const float*)d_in[8];
  const float* fc2_w  = (const float*)d_in[9];
  const float* fc2_b  = (const float*)d_in[10];
  const float* out_w  = (const float*)d_in[11];
  const float* out_b  = (const float*)d_in[12];
  const int* src      = (const int*)d_in[13];
  const int* dst      = (const int*)d_in[14];
  const int* mol_ids  = (const int*)d_in[15];

  char* ws = (char*)d_ws;
  u64 o = 0;
  auto alloc = [&](u64 bytes) {
    void* p = ws + o;
    o += (bytes + 255) & ~255ull;
    return p;
  };
  float* PQ     = (float*)alloc((u64)NA * DF * 4);
  float* sA     = (float*)alloc((u64)NA * DF * 4);
  float* sB     = (float*)alloc((u64)NA * DF * 4);
  ushort_t* WpB = (ushort_t*)alloc(3 * 16384 * 2);
  ushort_t* WhB = (ushort_t*)alloc(3 * 4096 * 2);
  ushort_t* WoB = (ushort_t*)alloc(3 * 8192 * 2);
  float* molr   = (float*)alloc((u64)NMOL * DF * 4);
  int* counts   = (int*)alloc((u64)NA * 4);
  int* row_ptr  = (int*)alloc((u64)(NA + 1) * 4);
  int* cursor   = (int*)alloc((u64)NA * 4);
  int* dst_s    = (int*)alloc((u64)NE * 4);
  int* src_s    = (int*)alloc((u64)NE * 4);
  int* scan_tmp = (int*)alloc((u64)NA * 4);
  int* blk_sums = (int*)alloc(64 * 4);
  (void)ws_size; (void)in_sizes; (void)n_in; (void)out_size;

  const int NSCAN = (NA + 1023) / 1024;  // 49

  hipMemsetAsync(counts, 0, (u64)NA * 4, stream);
  hipMemsetAsync(cursor, 0, (u64)NA * 4, stream);
  hipMemsetAsync(molr, 0, (u64)NMOL * DF * 4, stream);

  pack_weights<<<336, 256, 0, stream>>>(Win, Wh, Wout, WpB, WhB, WoB);
  count_edges<<<(NE + 255) / 256, 256, 0, stream>>>(dst, counts);
  scan_phase1<<<NSCAN, 1024, 0, stream>>>(counts, scan_tmp, blk_sums);
  scan_phase2<<<1, 64, 0, stream>>>(blk_sums, NSCAN);
  scan_phase3<<<NSCAN, 1024, 0, stream>>>(scan_tmp, blk_sums, row_ptr);
  fill_edges<<<(NE + 255) / 256, 256, 0, stream>>>(src, dst, row_ptr, cursor, dst_s, src_s);

  const float* scur = states;
  float* snxt = sA;
  for (int t = 0; t < NSTEP; t++) {
    node_proj<<<(NA + 63) / 64, 256, 0, stream>>>(scur, WpB + t * 16384, PQ);
    hipMemsetAsync(snxt, 0, (u64)NA * DF * 4, stream);
    edge_mlp<<<(NE + 127) / 128, 256, 0, stream>>>(
        PQ, WhB + t * 4096, WoB + t * 8192,
        b_in + t * 64, b_h + t * 64, b_out + t * 128, dst_s, src_s, snxt);
    scur = snxt;
    snxt = (snxt == sA) ? sB : sA;
  }
  mol_agg<<<(int)(((u64)NA * DF + 255) / 256), 256, 0, stream>>>(scur, mol_ids, molr);
  final_mlp<<<NMOL, 64, 0, stream>>>(molr, fc1_w, fc1_b, fc2_w, fc2_b, out_w, out_b,
                                     (float*)d_out);
}

// Round 5
// 575.343 us; speedup vs baseline: 4.4369x; 1.0560x over previous
//
#include <hip/hip_runtime.h>

typedef unsigned long long u64;
typedef unsigned short ushort_t;

#define NA 50000
#define NE 400000
#define DF 128
#define HID 64
#define NMOL 256
#define NOUT 32
#define NSTEP 3

typedef __attribute__((ext_vector_type(8))) short short8;
typedef __attribute__((ext_vector_type(4))) float f32x4;

static __device__ __forceinline__ ushort_t f2bf(float f) {
  union { float f; unsigned u; } v; v.f = f;
  unsigned r = v.u + 0x7fffu + ((v.u >> 16) & 1u);
  return (ushort_t)(r >> 16);
}
static __device__ __forceinline__ float bf2f(unsigned b) {
  union { unsigned u; float f; } v; v.u = b << 16;
  return v.f;
}

// ---------------- pack weights into MFMA B-fragment order (bf16) -----------
// B-frag for mfma_f32_16x16x32_bf16: lane l holds B[k=(l>>4)*8+j][n=l&15].
__global__ void pack_weights(const float* __restrict__ Win,
                             const float* __restrict__ Wh,
                             const float* __restrict__ Wout,
                             ushort_t* __restrict__ WpB,
                             ushort_t* __restrict__ WhB,
                             ushort_t* __restrict__ WoB) {
  int g = blockIdx.x * 256 + threadIdx.x;
  if (g < 3 * 16384) {
    int tt = g / 16384, r = g % 16384;
    int j = r & 7, lane = (r >> 3) & 63, f = r >> 9;
    int kc = f & 3, nt = f >> 2;
    int k = kc * 32 + (lane >> 4) * 8 + j;
    int n = nt * 16 + (lane & 15);
    float v = (n < 64) ? Win[tt * 16384 + k * 64 + n]
                       : Win[tt * 16384 + (128 + k) * 64 + (n - 64)];
    WpB[g] = f2bf(v);
  }
  int g2 = g - 3 * 16384;
  if (g2 >= 0 && g2 < 3 * 4096) {
    int tt = g2 / 4096, r = g2 % 4096;
    int j = r & 7, lane = (r >> 3) & 63, f = r >> 9;
    int kc = f & 1, nt = f >> 1;
    int k = kc * 32 + (lane >> 4) * 8 + j;
    int n = nt * 16 + (lane & 15);
    WhB[g2] = f2bf(Wh[tt * 4096 + k * 64 + n]);
  }
  int g3 = g2 - 3 * 4096;
  if (g3 >= 0 && g3 < 3 * 8192) {
    int tt = g3 / 8192, r = g3 % 8192;
    int j = r & 7, lane = (r >> 3) & 63, f = r >> 9;
    int kc = f & 1, nt = f >> 1;
    int k = kc * 32 + (lane >> 4) * 8 + j;
    int n = nt * 16 + (lane & 15);
    WoB[g3] = f2bf(Wout[tt * 8192 + k * 128 + n]);
  }
}

// ---------------- CSR build (sort edges by dst) ----------------
__global__ void count_edges(const int* __restrict__ dst, int* __restrict__ counts) {
  int e = blockIdx.x * 256 + threadIdx.x;
  if (e < NE) atomicAdd(&counts[dst[e]], 1);
}

__global__ void scan_phase1(const int* __restrict__ counts, int* __restrict__ tmp,
                            int* __restrict__ blk) {
  __shared__ int sh[1024];
  int t = threadIdx.x;
  int i = blockIdx.x * 1024 + t;
  int v = (i < NA) ? counts[i] : 0;
  sh[t] = v;
  __syncthreads();
  for (int off = 1; off < 1024; off <<= 1) {
    int x = (t >= off) ? sh[t - off] : 0;
    __syncthreads();
    sh[t] += x;
    __syncthreads();
  }
  if (i < NA) tmp[i] = sh[t];
  if (t == 1023) blk[blockIdx.x] = sh[1023];
}

__global__ void scan_phase2(int* __restrict__ blk, int nblk) {
  __shared__ int sh[64];
  int t = threadIdx.x;
  sh[t] = (t < nblk) ? blk[t] : 0;
  __syncthreads();
  if (t == 0) {
    int run = 0;
    for (int k = 0; k < nblk; k++) { int c = sh[k]; sh[k] = run; run += c; }
  }
  __syncthreads();
  if (t < nblk) blk[t] = sh[t];
}

__global__ void scan_phase3(const int* __restrict__ tmp, const int* __restrict__ blk,
                            int* __restrict__ row_ptr) {
  int i = blockIdx.x * 1024 + threadIdx.x;
  if (i < NA) row_ptr[i + 1] = tmp[i] + blk[blockIdx.x];
  if (i == 0 && blockIdx.x == 0) row_ptr[0] = 0;
}

__global__ void fill_edges(const int* __restrict__ src, const int* __restrict__ dst,
                           const int* __restrict__ row_ptr, int* __restrict__ cursor,
                           int* __restrict__ dst_s, int* __restrict__ src_s) {
  int e = blockIdx.x * 256 + threadIdx.x;
  if (e < NE) {
    int d = dst[e];
    int pos = row_ptr[d] + atomicAdd(&cursor[d], 1);
    dst_s[pos] = d;
    src_s[pos] = src[e];
  }
}

// ---------------- molecule CSR ----------------
__global__ void count_mols(const int* __restrict__ mol_ids, int* __restrict__ mcnt) {
  int i = blockIdx.x * 256 + threadIdx.x;
  if (i < NA) atomicAdd(&mcnt[mol_ids[i]], 1);
}

__global__ void scan_mols(const int* __restrict__ mcnt, int* __restrict__ mrow) {
  __shared__ int sh[NMOL];
  int t = threadIdx.x;
  sh[t] = mcnt[t];
  __syncthreads();
  for (int off = 1; off < NMOL; off <<= 1) {
    int x = (t >= off) ? sh[t - off] : 0;
    __syncthreads();
    sh[t] += x;
    __syncthreads();
  }
  mrow[t + 1] = sh[t];
  if (t == 0) mrow[0] = 0;
}

__global__ void fill_mols(const int* __restrict__ mol_ids, const int* __restrict__ mrow,
                          int* __restrict__ mcur, int* __restrict__ mol_sorted) {
  int i = blockIdx.x * 256 + threadIdx.x;
  if (i < NA) {
    int m = mol_ids[i];
    int pos = mrow[m] + atomicAdd(&mcur[m], 1);
    mol_sorted[pos] = i;
  }
}

// ---------------- node projection: PQ = s @ W'  (MFMA bf16, LDS-free) ------
__global__ __launch_bounds__(256) void node_proj(const float* __restrict__ s_in,
                                                 const ushort_t* __restrict__ WpB,
                                                 float* __restrict__ PQ) {
  const int t = threadIdx.x;
  const int lane = t & 63, wv = t >> 6, quad = lane >> 4, l15 = lane & 15;
  const int n0 = blockIdx.x * 64 + wv * 16;
  int n = n0 + l15; if (n >= NA) n = NA - 1;
  union { short8 v; ushort_t u[8]; } a[4];
#pragma unroll
  for (int c = 0; c < 4; c++) {
    const float* p = s_in + (u64)n * 128 + c * 32 + quad * 8;
    float4 f0 = *(const float4*)(p);
    float4 f1 = *(const float4*)(p + 4);
    a[c].u[0] = f2bf(f0.x); a[c].u[1] = f2bf(f0.y);
    a[c].u[2] = f2bf(f0.z); a[c].u[3] = f2bf(f0.w);
    a[c].u[4] = f2bf(f1.x); a[c].u[5] = f2bf(f1.y);
    a[c].u[6] = f2bf(f1.z); a[c].u[7] = f2bf(f1.w);
  }
#pragma unroll
  for (int nt = 0; nt < 8; nt++) {
    f32x4 acc = {0.f, 0.f, 0.f, 0.f};
#pragma unroll
    for (int c = 0; c < 4; c++) {
      short8 b = *(const short8*)&WpB[((nt * 4 + c) * 64 + lane) * 8];
      acc = __builtin_amdgcn_mfma_f32_16x16x32_bf16(a[c].v, b, acc, 0, 0, 0);
    }
#pragma unroll
    for (int r = 0; r < 4; r++) {
      int nn = n0 + quad * 4 + r;
      if (nn < NA) PQ[(u64)nn * 128 + nt * 16 + l15] = acc[r];
    }
  }
}

// ------------- fused edge MLP (MFMA) -> streamed packed-bf16 messages ------
// 128 edges / workgroup (4 waves x 2 tiles of 16 edges). No atomics.
// m_buf[e][pc]: dword pc = k*16+l15 packs cols (32k+l15, 32k+16+l15).
__global__ __launch_bounds__(256) void edge_msg(
    const float* __restrict__ PQ,
    const ushort_t* __restrict__ WhB, const ushort_t* __restrict__ WoB,
    const float* __restrict__ b_in, const float* __restrict__ b_h,
    const float* __restrict__ b_out,
    const int* __restrict__ dst_s, const int* __restrict__ src_s,
    unsigned* __restrict__ m_buf) {
  __shared__ int eds[128], ess[128];
  __shared__ ushort_t h2s[8][16 * 72];  // per-(wave,i) 16 x 64 bf16, pitch 72
  const int t = threadIdx.x;
  const int lane = t & 63, wv = t >> 6, quad = lane >> 4, l15 = lane & 15;
  const long long e0 = (long long)blockIdx.x * 128;

  if (t < 128) {
    long long e = e0 + t; if (e >= NE) e = NE - 1;
    eds[t] = dst_s[e]; ess[t] = src_s[e];
  }
  float bh[4], bo[8];
#pragma unroll
  for (int nt = 0; nt < 4; nt++) bh[nt] = b_h[nt * 16 + l15];
#pragma unroll
  for (int nt = 0; nt < 8; nt++) bo[nt] = b_out[nt * 16 + l15];
  __syncthreads();

#pragma unroll
  for (int i = 0; i < 2; i++) {
    const int ebl = wv * 32 + i * 16;  // block-local tile base
    const int da = eds[ebl + l15], sa = ess[ebl + l15];

    // A-frag of h1 = relu(P[dst] + Q[src] + b_in) built directly in registers
    union { short8 v; ushort_t u[8]; } a1[2];
#pragma unroll
    for (int c = 0; c < 2; c++) {
      const int col = c * 32 + quad * 8;
      float4 p0 = *(const float4*)(PQ + (u64)da * 128 + col);
      float4 p1 = *(const float4*)(PQ + (u64)da * 128 + col + 4);
      float4 q0 = *(const float4*)(PQ + (u64)sa * 128 + 64 + col);
      float4 q1 = *(const float4*)(PQ + (u64)sa * 128 + 64 + col + 4);
      float4 bi0 = *(const float4*)(b_in + col);
      float4 bi1 = *(const float4*)(b_in + col + 4);
      a1[c].u[0] = f2bf(fmaxf(p0.x + q0.x + bi0.x, 0.f));
      a1[c].u[1] = f2bf(fmaxf(p0.y + q0.y + bi0.y, 0.f));
      a1[c].u[2] = f2bf(fmaxf(p0.z + q0.z + bi0.z, 0.f));
      a1[c].u[3] = f2bf(fmaxf(p0.w + q0.w + bi0.w, 0.f));
      a1[c].u[4] = f2bf(fmaxf(p1.x + q1.x + bi1.x, 0.f));
      a1[c].u[5] = f2bf(fmaxf(p1.y + q1.y + bi1.y, 0.f));
      a1[c].u[6] = f2bf(fmaxf(p1.z + q1.z + bi1.z, 0.f));
      a1[c].u[7] = f2bf(fmaxf(p1.w + q1.w + bi1.w, 0.f));
    }

    // h2 = relu(h1 @ Wh + b_h)
    f32x4 acc1[4];
#pragma unroll
    for (int nt = 0; nt < 4; nt++) {
      f32x4 acc = {0.f, 0.f, 0.f, 0.f};
#pragma unroll
      for (int c = 0; c < 2; c++) {
        short8 b = *(const short8*)&WhB[((nt * 2 + c) * 64 + lane) * 8];
        acc = __builtin_amdgcn_mfma_f32_16x16x32_bf16(a1[c].v, b, acc, 0, 0, 0);
      }
      acc1[nt] = acc;
    }
    // D-layout -> row-major LDS (wave-private; same-wave RAW via lgkmcnt)
    ushort_t* hb = h2s[wv * 2 + i];
#pragma unroll
    for (int nt = 0; nt < 4; nt++)
#pragma unroll
      for (int r = 0; r < 4; r++)
        hb[(quad * 4 + r) * 72 + nt * 16 + l15] =
            f2bf(fmaxf(acc1[nt][r] + bh[nt], 0.f));

    union { short8 v; ushort_t u[8]; } a2[2];
#pragma unroll
    for (int c = 0; c < 2; c++)
      a2[c].v = *(const short8*)&hb[l15 * 72 + c * 32 + quad * 8];

    // m = relu(h2 @ Wout + b_out)
    f32x4 acc2[8];
#pragma unroll
    for (int nt = 0; nt < 8; nt++) {
      f32x4 acc = {0.f, 0.f, 0.f, 0.f};
#pragma unroll
      for (int c = 0; c < 2; c++) {
        short8 b = *(const short8*)&WoB[((nt * 2 + c) * 64 + lane) * 8];
        acc = __builtin_amdgcn_mfma_f32_16x16x32_bf16(a2[c].v, b, acc, 0, 0, 0);
      }
      acc2[nt] = acc;
    }

    // stream out packed bf16 (cols 32k+l15 | 32k+16+l15), coalesced, no atomics
#pragma unroll
    for (int r = 0; r < 4; r++) {
      long long e = e0 + ebl + quad * 4 + r;
      if (e < NE) {
        unsigned* row = m_buf + (u64)e * 64;
#pragma unroll
        for (int k = 0; k < 4; k++) {
          float lo = fmaxf(acc2[2 * k][r] + bo[2 * k], 0.f);
          float hi = fmaxf(acc2[2 * k + 1][r] + bo[2 * k + 1], 0.f);
          row[k * 16 + l15] = (unsigned)f2bf(lo) | ((unsigned)f2bf(hi) << 16);
        }
      }
    }
  }
}

// -------- dst aggregation: wave per dst, contiguous CSR rows, no atomics ---
__global__ __launch_bounds__(256) void agg_dst(const unsigned* __restrict__ m_buf,
                                               const int* __restrict__ row_ptr,
                                               float* __restrict__ s_next) {
  int w = (blockIdx.x * 256 + threadIdx.x) >> 6;  // dst id
  int lane = threadIdx.x & 63;
  if (w >= NA) return;
  int beg = row_ptr[w], end = row_ptr[w + 1];
  float a0 = 0.f, a1 = 0.f;
  for (int e = beg; e < end; e++) {
    unsigned d = m_buf[(u64)e * 64 + lane];
    a0 += bf2f(d & 0xffffu);
    a1 += bf2f(d >> 16);
  }
  int k = lane >> 4, l15 = lane & 15;
  s_next[(u64)w * 128 + k * 32 + l15] = a0;
  s_next[(u64)w * 128 + k * 32 + 16 + l15] = a1;
}

// ---------------- molecule aggregation (CSR, no atomics) ----------------
__global__ void agg_mol(const float* __restrict__ s_fin,
                        const int* __restrict__ mol_sorted,
                        const int* __restrict__ mrow,
                        float* __restrict__ mol_repr) {
  int m = blockIdx.x, c = threadIdx.x;  // 128 threads
  int beg = mrow[m], end = mrow[m + 1];
  float acc = 0.f;
  for (int i = beg; i < end; i++)
    acc += s_fin[(u64)mol_sorted[i] * 128 + c];
  mol_repr[(u64)m * 128 + c] = acc;
}

// ---------------- final tiny MLP per molecule ----------------
__global__ void final_mlp(const float* __restrict__ mol_repr,
                          const float* __restrict__ fc1_w, const float* __restrict__ fc1_b,
                          const float* __restrict__ fc2_w, const float* __restrict__ fc2_b,
                          const float* __restrict__ out_w, const float* __restrict__ out_b,
                          float* __restrict__ out) {
  int m = blockIdx.x, j = threadIdx.x;
  __shared__ float h1sh[64], h2sh[64];
  const float* mr = mol_repr + (u64)m * DF;
  float acc = fc1_b[j];
  for (int d = 0; d < DF; d++) acc = fmaf(mr[d], fc1_w[d * 64 + j], acc);
  h1sh[j] = fmaxf(acc, 0.f);
  __syncthreads();
  acc = fc2_b[j];
  for (int k = 0; k < 64; k++) acc = fmaf(h1sh[k], fc2_w[k * 64 + j], acc);
  h2sh[j] = fmaxf(acc, 0.f);
  __syncthreads();
  if (j < NOUT) {
    acc = out_b[j];
    for (int k = 0; k < 64; k++) acc = fmaf(h2sh[k], out_w[k * NOUT + j], acc);
    out[(u64)m * NOUT + j] = acc;
  }
}

extern "C" void kernel_launch(void* const* d_in, const int* in_sizes, int n_in,
                              void* d_out, int out_size, void* d_ws, size_t ws_size,
                              hipStream_t stream) {
  const float* states = (const float*)d_in[0];
  const float* Win    = (const float*)d_in[1];
  const float* b_in   = (const float*)d_in[2];
  const float* Wh     = (const float*)d_in[3];
  const float* b_h    = (const float*)d_in[4];
  const float* Wout   = (const float*)d_in[5];
  const float* b_out  = (const float*)d_in[6];
  const float* fc1_w  = (const float*)d_in[7];
  const float* fc1_b  = (const float*)d_in[8];
  const float* fc2_w  = (const float*)d_in[9];
  const float* fc2_b  = (const float*)d_in[10];
  const float* out_w  = (const float*)d_in[11];
  const float* out_b  = (const float*)d_in[12];
  const int* src      = (const int*)d_in[13];
  const int* dst      = (const int*)d_in[14];
  const int* mol_ids  = (const int*)d_in[15];

  char* ws = (char*)d_ws;
  u64 o = 0;
  auto alloc = [&](u64 bytes) {
    void* p = ws + o;
    o += (bytes + 255) & ~255ull;
    return p;
  };
  unsigned* m_buf = (unsigned*)alloc((u64)NE * 64 * 4);   // 102.4 MB
  float* PQ     = (float*)alloc((u64)NA * DF * 4);
  float* sA     = (float*)alloc((u64)NA * DF * 4);
  ushort_t* WpB = (ushort_t*)alloc(3 * 16384 * 2);
  ushort_t* WhB = (ushort_t*)alloc(3 * 4096 * 2);
  ushort_t* WoB = (ushort_t*)alloc(3 * 8192 * 2);
  float* molr   = (float*)alloc((u64)NMOL * DF * 4);
  // zero-init counter block (single memset)
  char* zbase   = ws + o;
  int* counts   = (int*)alloc((u64)NA * 4);
  int* cursor   = (int*)alloc((u64)NA * 4);
  int* mcnt     = (int*)alloc(NMOL * 4);
  int* mcur     = (int*)alloc(NMOL * 4);
  u64 zbytes    = (u64)((ws + o) - zbase);
  int* row_ptr  = (int*)alloc((u64)(NA + 1) * 4);
  int* mrow     = (int*)alloc((NMOL + 1) * 4);
  int* dst_s    = (int*)alloc((u64)NE * 4);
  int* src_s    = (int*)alloc((u64)NE * 4);
  int* mol_sorted = (int*)alloc((u64)NA * 4);
  int* scan_tmp = (int*)alloc((u64)NA * 4);
  int* blk_sums = (int*)alloc(64 * 4);
  (void)ws_size; (void)in_sizes; (void)n_in; (void)out_size;

  const int NSCAN = (NA + 1023) / 1024;  // 49

  hipMemsetAsync(zbase, 0, zbytes, stream);

  pack_weights<<<336, 256, 0, stream>>>(Win, Wh, Wout, WpB, WhB, WoB);
  count_edges<<<(NE + 255) / 256, 256, 0, stream>>>(dst, counts);
  scan_phase1<<<NSCAN, 1024, 0, stream>>>(counts, scan_tmp, blk_sums);
  scan_phase2<<<1, 64, 0, stream>>>(blk_sums, NSCAN);
  scan_phase3<<<NSCAN, 1024, 0, stream>>>(scan_tmp, blk_sums, row_ptr);
  fill_edges<<<(NE + 255) / 256, 256, 0, stream>>>(src, dst, row_ptr, cursor, dst_s, src_s);
  count_mols<<<(NA + 255) / 256, 256, 0, stream>>>(mol_ids, mcnt);
  scan_mols<<<1, NMOL, 0, stream>>>(mcnt, mrow);
  fill_mols<<<(NA + 255) / 256, 256, 0, stream>>>(mol_ids, mrow, mcur, mol_sorted);

  const float* scur = states;
  for (int t = 0; t < NSTEP; t++) {
    node_proj<<<(NA + 63) / 64, 256, 0, stream>>>(scur, WpB + t * 16384, PQ);
    edge_msg<<<(NE + 127) / 128, 256, 0, stream>>>(
        PQ, WhB + t * 4096, WoB + t * 8192,
        b_in + t * 64, b_h + t * 64, b_out + t * 128, dst_s, src_s, m_buf);
    agg_dst<<<(NA * 64 + 255) / 256, 256, 0, stream>>>(m_buf, row_ptr, sA);
    scur = sA;
  }
  agg_mol<<<NMOL, 128, 0, stream>>>(sA, mol_sorted, mrow, molr);
  final_mlp<<<NMOL, 64, 0, stream>>>(molr, fc1_w, fc1_b, fc2_w, fc2_b, out_w, out_b,
                                     (float*)d_out);
}

// Round 6
// 515.881 us; speedup vs baseline: 4.9483x; 1.1153x over previous
//
#include <hip/hip_runtime.h>

typedef unsigned long long u64;
typedef unsigned short ushort_t;

#define NA 50000
#define NE 400000
#define DF 128
#define HID 64
#define NMOL 256
#define NOUT 32
#define NSTEP 3

typedef __attribute__((ext_vector_type(8))) short short8;
typedef __attribute__((ext_vector_type(8))) unsigned short ushort8;
typedef __attribute__((ext_vector_type(4))) float f32x4;

static __device__ __forceinline__ ushort_t f2bf(float f) {
  union { float f; unsigned u; } v; v.f = f;
  unsigned r = v.u + 0x7fffu + ((v.u >> 16) & 1u);
  return (ushort_t)(r >> 16);
}
static __device__ __forceinline__ float bf2f(unsigned b) {
  union { unsigned u; float f; } v; v.u = b << 16;
  return v.f;
}

// ---------------- pack weights into MFMA B-fragment order (bf16) -----------
// B-frag for mfma_f32_16x16x32_bf16: lane l holds B[k=(l>>4)*8+j][n=l&15].
__global__ void pack_weights(const float* __restrict__ Win,
                             const float* __restrict__ Wh,
                             const float* __restrict__ Wout,
                             ushort_t* __restrict__ WpB,
                             ushort_t* __restrict__ WhB,
                             ushort_t* __restrict__ WoB) {
  int g = blockIdx.x * 256 + threadIdx.x;
  if (g < 3 * 16384) {
    int tt = g / 16384, r = g % 16384;
    int j = r & 7, lane = (r >> 3) & 63, f = r >> 9;
    int kc = f & 3, nt = f >> 2;
    int k = kc * 32 + (lane >> 4) * 8 + j;
    int n = nt * 16 + (lane & 15);
    float v = (n < 64) ? Win[tt * 16384 + k * 64 + n]
                       : Win[tt * 16384 + (128 + k) * 64 + (n - 64)];
    WpB[g] = f2bf(v);
  }
  int g2 = g - 3 * 16384;
  if (g2 >= 0 && g2 < 3 * 4096) {
    int tt = g2 / 4096, r = g2 % 4096;
    int j = r & 7, lane = (r >> 3) & 63, f = r >> 9;
    int kc = f & 1, nt = f >> 1;
    int k = kc * 32 + (lane >> 4) * 8 + j;
    int n = nt * 16 + (lane & 15);
    WhB[g2] = f2bf(Wh[tt * 4096 + k * 64 + n]);
  }
  int g3 = g2 - 3 * 4096;
  if (g3 >= 0 && g3 < 3 * 8192) {
    int tt = g3 / 8192, r = g3 % 8192;
    int j = r & 7, lane = (r >> 3) & 63, f = r >> 9;
    int kc = f & 1, nt = f >> 1;
    int k = kc * 32 + (lane >> 4) * 8 + j;
    int n = nt * 16 + (lane & 15);
    WoB[g3] = f2bf(Wout[tt * 8192 + k * 128 + n]);
  }
}

// ---------------- CSR build (sort edges by dst) ----------------
__global__ void count_edges(const int* __restrict__ dst, int* __restrict__ counts) {
  int e = blockIdx.x * 256 + threadIdx.x;
  if (e < NE) atomicAdd(&counts[dst[e]], 1);
}

__global__ void scan_phase1(const int* __restrict__ counts, int* __restrict__ tmp,
                            int* __restrict__ blk) {
  __shared__ int sh[1024];
  int t = threadIdx.x;
  int i = blockIdx.x * 1024 + t;
  int v = (i < NA) ? counts[i] : 0;
  sh[t] = v;
  __syncthreads();
  for (int off = 1; off < 1024; off <<= 1) {
    int x = (t >= off) ? sh[t - off] : 0;
    __syncthreads();
    sh[t] += x;
    __syncthreads();
  }
  if (i < NA) tmp[i] = sh[t];
  if (t == 1023) blk[blockIdx.x] = sh[1023];
}

__global__ void scan_phase2(int* __restrict__ blk, int nblk) {
  __shared__ int sh[64];
  int t = threadIdx.x;
  sh[t] = (t < nblk) ? blk[t] : 0;
  __syncthreads();
  if (t == 0) {
    int run = 0;
    for (int k = 0; k < nblk; k++) { int c = sh[k]; sh[k] = run; run += c; }
  }
  __syncthreads();
  if (t < nblk) blk[t] = sh[t];
}

__global__ void scan_phase3(const int* __restrict__ tmp, const int* __restrict__ blk,
                            int* __restrict__ row_ptr) {
  int i = blockIdx.x * 1024 + threadIdx.x;
  if (i < NA) row_ptr[i + 1] = tmp[i] + blk[blockIdx.x];
  if (i == 0 && blockIdx.x == 0) row_ptr[0] = 0;
}

__global__ void fill_edges(const int* __restrict__ src, const int* __restrict__ dst,
                           const int* __restrict__ row_ptr, int* __restrict__ cursor,
                           int* __restrict__ dst_s, int* __restrict__ src_s) {
  int e = blockIdx.x * 256 + threadIdx.x;
  if (e < NE) {
    int d = dst[e];
    int pos = row_ptr[d] + atomicAdd(&cursor[d], 1);
    dst_s[pos] = d;
    src_s[pos] = src[e];
  }
}

// ---------------- molecule CSR ----------------
__global__ void count_mols(const int* __restrict__ mol_ids, int* __restrict__ mcnt) {
  int i = blockIdx.x * 256 + threadIdx.x;
  if (i < NA) atomicAdd(&mcnt[mol_ids[i]], 1);
}

__global__ void scan_mols(const int* __restrict__ mcnt, int* __restrict__ mrow) {
  __shared__ int sh[NMOL];
  int t = threadIdx.x;
  sh[t] = mcnt[t];
  __syncthreads();
  for (int off = 1; off < NMOL; off <<= 1) {
    int x = (t >= off) ? sh[t - off] : 0;
    __syncthreads();
    sh[t] += x;
    __syncthreads();
  }
  mrow[t + 1] = sh[t];
  if (t == 0) mrow[0] = 0;
}

__global__ void fill_mols(const int* __restrict__ mol_ids, const int* __restrict__ mrow,
                          int* __restrict__ mcur, int* __restrict__ mol_sorted) {
  int i = blockIdx.x * 256 + threadIdx.x;
  if (i < NA) {
    int m = mol_ids[i];
    int pos = mrow[m] + atomicAdd(&mcur[m], 1);
    mol_sorted[pos] = i;
  }
}

// ---------------- node projection: PQb = bf16(s @ W')  (MFMA, LDS-free) ----
__global__ __launch_bounds__(256) void node_proj(const float* __restrict__ s_in,
                                                 const ushort_t* __restrict__ WpB,
                                                 ushort_t* __restrict__ PQb) {
  const int t = threadIdx.x;
  const int lane = t & 63, wv = t >> 6, quad = lane >> 4, l15 = lane & 15;
  const int n0 = blockIdx.x * 64 + wv * 16;
  int n = n0 + l15; if (n >= NA) n = NA - 1;
  union { short8 v; ushort_t u[8]; } a[4];
#pragma unroll
  for (int c = 0; c < 4; c++) {
    const float* p = s_in + (u64)n * 128 + c * 32 + quad * 8;
    float4 f0 = *(const float4*)(p);
    float4 f1 = *(const float4*)(p + 4);
    a[c].u[0] = f2bf(f0.x); a[c].u[1] = f2bf(f0.y);
    a[c].u[2] = f2bf(f0.z); a[c].u[3] = f2bf(f0.w);
    a[c].u[4] = f2bf(f1.x); a[c].u[5] = f2bf(f1.y);
    a[c].u[6] = f2bf(f1.z); a[c].u[7] = f2bf(f1.w);
  }
#pragma unroll
  for (int nt = 0; nt < 8; nt++) {
    f32x4 acc = {0.f, 0.f, 0.f, 0.f};
#pragma unroll
    for (int c = 0; c < 4; c++) {
      short8 b = *(const short8*)&WpB[((nt * 4 + c) * 64 + lane) * 8];
      acc = __builtin_amdgcn_mfma_f32_16x16x32_bf16(a[c].v, b, acc, 0, 0, 0);
    }
#pragma unroll
    for (int r = 0; r < 4; r++) {
      int nn = n0 + quad * 4 + r;
      if (nn < NA) PQb[(u64)nn * 128 + nt * 16 + l15] = f2bf(acc[r]);
    }
  }
}

// ------------- fused edge MLP (MFMA) -> streamed packed-bf16 messages ------
// 128 edges / workgroup (4 waves x 2 tiles of 16 edges). No atomics.
__global__ __launch_bounds__(256) void edge_msg(
    const ushort_t* __restrict__ PQb,
    const ushort_t* __restrict__ WhB, const ushort_t* __restrict__ WoB,
    const float* __restrict__ b_in, const float* __restrict__ b_h,
    const float* __restrict__ b_out,
    const int* __restrict__ dst_s, const int* __restrict__ src_s,
    unsigned* __restrict__ m_buf) {
  __shared__ int eds[128], ess[128];
  __shared__ ushort_t h2s[8][16 * 72];  // per-(wave,i) 16 x 64 bf16, pitch 72
  const int t = threadIdx.x;
  const int lane = t & 63, wv = t >> 6, quad = lane >> 4, l15 = lane & 15;
  const long long e0 = (long long)blockIdx.x * 128;

  if (t < 128) {
    long long e = e0 + t; if (e >= NE) e = NE - 1;
    eds[t] = dst_s[e]; ess[t] = src_s[e];
  }
  float bh[4], bo[8];
#pragma unroll
  for (int nt = 0; nt < 4; nt++) bh[nt] = b_h[nt * 16 + l15];
#pragma unroll
  for (int nt = 0; nt < 8; nt++) bo[nt] = b_out[nt * 16 + l15];
  __syncthreads();

#pragma unroll
  for (int i = 0; i < 2; i++) {
    const int ebl = wv * 32 + i * 16;  // block-local tile base
    const int da = eds[ebl + l15], sa = ess[ebl + l15];

    // A-frag of h1 = relu(P[dst] + Q[src] + b_in); 16B bf16 gathers
    union { short8 v; ushort_t u[8]; } a1[2];
#pragma unroll
    for (int c = 0; c < 2; c++) {
      const int col = c * 32 + quad * 8;
      union { ushort8 v; ushort_t u[8]; } pv, qv;
      pv.v = *(const ushort8*)&PQb[(u64)da * 128 + col];
      qv.v = *(const ushort8*)&PQb[(u64)sa * 128 + 64 + col];
      float4 bi0 = *(const float4*)(b_in + col);
      float4 bi1 = *(const float4*)(b_in + col + 4);
      a1[c].u[0] = f2bf(fmaxf(bf2f(pv.u[0]) + bf2f(qv.u[0]) + bi0.x, 0.f));
      a1[c].u[1] = f2bf(fmaxf(bf2f(pv.u[1]) + bf2f(qv.u[1]) + bi0.y, 0.f));
      a1[c].u[2] = f2bf(fmaxf(bf2f(pv.u[2]) + bf2f(qv.u[2]) + bi0.z, 0.f));
      a1[c].u[3] = f2bf(fmaxf(bf2f(pv.u[3]) + bf2f(qv.u[3]) + bi0.w, 0.f));
      a1[c].u[4] = f2bf(fmaxf(bf2f(pv.u[4]) + bf2f(qv.u[4]) + bi1.x, 0.f));
      a1[c].u[5] = f2bf(fmaxf(bf2f(pv.u[5]) + bf2f(qv.u[5]) + bi1.y, 0.f));
      a1[c].u[6] = f2bf(fmaxf(bf2f(pv.u[6]) + bf2f(qv.u[6]) + bi1.z, 0.f));
      a1[c].u[7] = f2bf(fmaxf(bf2f(pv.u[7]) + bf2f(qv.u[7]) + bi1.w, 0.f));
    }

    // h2 = relu(h1 @ Wh + b_h)
    f32x4 acc1[4];
#pragma unroll
    for (int nt = 0; nt < 4; nt++) {
      f32x4 acc = {0.f, 0.f, 0.f, 0.f};
#pragma unroll
      for (int c = 0; c < 2; c++) {
        short8 b = *(const short8*)&WhB[((nt * 2 + c) * 64 + lane) * 8];
        acc = __builtin_amdgcn_mfma_f32_16x16x32_bf16(a1[c].v, b, acc, 0, 0, 0);
      }
      acc1[nt] = acc;
    }
    // D-layout -> row-major LDS (wave-private; same-wave RAW via lgkmcnt)
    ushort_t* hb = h2s[wv * 2 + i];
#pragma unroll
    for (int nt = 0; nt < 4; nt++)
#pragma unroll
      for (int r = 0; r < 4; r++)
        hb[(quad * 4 + r) * 72 + nt * 16 + l15] =
            f2bf(fmaxf(acc1[nt][r] + bh[nt], 0.f));

    union { short8 v; ushort_t u[8]; } a2[2];
#pragma unroll
    for (int c = 0; c < 2; c++)
      a2[c].v = *(const short8*)&hb[l15 * 72 + c * 32 + quad * 8];

    // m = relu(h2 @ Wout + b_out)
    f32x4 acc2[8];
#pragma unroll
    for (int nt = 0; nt < 8; nt++) {
      f32x4 acc = {0.f, 0.f, 0.f, 0.f};
#pragma unroll
      for (int c = 0; c < 2; c++) {
        short8 b = *(const short8*)&WoB[((nt * 2 + c) * 64 + lane) * 8];
        acc = __builtin_amdgcn_mfma_f32_16x16x32_bf16(a2[c].v, b, acc, 0, 0, 0);
      }
      acc2[nt] = acc;
    }

    // stream out packed bf16 (cols 32k+l15 | 32k+16+l15), coalesced, no atomics
#pragma unroll
    for (int r = 0; r < 4; r++) {
      long long e = e0 + ebl + quad * 4 + r;
      if (e < NE) {
        unsigned* row = m_buf + (u64)e * 64;
#pragma unroll
        for (int k = 0; k < 4; k++) {
          float lo = fmaxf(acc2[2 * k][r] + bo[2 * k], 0.f);
          float hi = fmaxf(acc2[2 * k + 1][r] + bo[2 * k + 1], 0.f);
          row[k * 16 + l15] = (unsigned)f2bf(lo) | ((unsigned)f2bf(hi) << 16);
        }
      }
    }
  }
}

// -------- dst aggregation: wave per dst, contiguous CSR rows, no atomics ---
__global__ __launch_bounds__(256) void agg_dst(const unsigned* __restrict__ m_buf,
                                               const int* __restrict__ row_ptr,
                                               float* __restrict__ s_next) {
  int w = (blockIdx.x * 256 + threadIdx.x) >> 6;  // dst id
  int lane = threadIdx.x & 63;
  if (w >= NA) return;
  int beg = row_ptr[w], end = row_ptr[w + 1];
  float a0 = 0.f, a1 = 0.f;
  for (int e = beg; e < end; e++) {
    unsigned d = m_buf[(u64)e * 64 + lane];
    a0 += bf2f(d & 0xffffu);
    a1 += bf2f(d >> 16);
  }
  int k = lane >> 4, l15 = lane & 15;
  s_next[(u64)w * 128 + k * 32 + l15] = a0;
  s_next[(u64)w * 128 + k * 32 + 16 + l15] = a1;
}

// ------- molecule aggregation: chunked segmented sum over mol_sorted -------
// block = 128 consecutive sorted atoms, thread = column; flush on mol change.
__global__ __launch_bounds__(128) void agg_mol(const float* __restrict__ s_fin,
                                               const int* __restrict__ mol_sorted,
                                               const int* __restrict__ mol_ids,
                                               float* __restrict__ mol_repr) {
  __shared__ int rows[128], mids[128];
  const int c = threadIdx.x;
  const int base = blockIdx.x * 128;
  int n = NA - base; if (n > 128) n = 128;
  if (c < n) {
    int r = mol_sorted[base + c];
    rows[c] = r;
    mids[c] = mol_ids[r];
  }
  __syncthreads();
  float run = 0.f;
  int prev = mids[0];
#pragma unroll 4
  for (int i = 0; i < n; i++) {
    int m = mids[i];
    if (m != prev) {
      atomicAdd(&mol_repr[(u64)prev * 128 + c], run);
      run = 0.f; prev = m;
    }
    run += s_fin[(u64)rows[i] * 128 + c];
  }
  atomicAdd(&mol_repr[(u64)prev * 128 + c], run);
}

// ---------------- final tiny MLP per molecule ----------------
__global__ void final_mlp(const float* __restrict__ mol_repr,
                          const float* __restrict__ fc1_w, const float* __restrict__ fc1_b,
                          const float* __restrict__ fc2_w, const float* __restrict__ fc2_b,
                          const float* __restrict__ out_w, const float* __restrict__ out_b,
                          float* __restrict__ out) {
  int m = blockIdx.x, j = threadIdx.x;
  __shared__ float h1sh[64], h2sh[64];
  const float* mr = mol_repr + (u64)m * DF;
  float acc = fc1_b[j];
  for (int d = 0; d < DF; d++) acc = fmaf(mr[d], fc1_w[d * 64 + j], acc);
  h1sh[j] = fmaxf(acc, 0.f);
  __syncthreads();
  acc = fc2_b[j];
  for (int k = 0; k < 64; k++) acc = fmaf(h1sh[k], fc2_w[k * 64 + j], acc);
  h2sh[j] = fmaxf(acc, 0.f);
  __syncthreads();
  if (j < NOUT) {
    acc = out_b[j];
    for (int k = 0; k < 64; k++) acc = fmaf(h2sh[k], out_w[k * NOUT + j], acc);
    out[(u64)m * NOUT + j] = acc;
  }
}

extern "C" void kernel_launch(void* const* d_in, const int* in_sizes, int n_in,
                              void* d_out, int out_size, void* d_ws, size_t ws_size,
                              hipStream_t stream) {
  const float* states = (const float*)d_in[0];
  const float* Win    = (const float*)d_in[1];
  const float* b_in   = (const float*)d_in[2];
  const float* Wh     = (const float*)d_in[3];
  const float* b_h    = (const float*)d_in[4];
  const float* Wout   = (const float*)d_in[5];
  const float* b_out  = (const float*)d_in[6];
  const float* fc1_w  = (const float*)d_in[7];
  const float* fc1_b  = (const float*)d_in[8];
  const float* fc2_w  = (const float*)d_in[9];
  const float* fc2_b  = (const float*)d_in[10];
  const float* out_w  = (const float*)d_in[11];
  const float* out_b  = (const float*)d_in[12];
  const int* src      = (const int*)d_in[13];
  const int* dst      = (const int*)d_in[14];
  const int* mol_ids  = (const int*)d_in[15];

  char* ws = (char*)d_ws;
  u64 o = 0;
  auto alloc = [&](u64 bytes) {
    void* p = ws + o;
    o += (bytes + 255) & ~255ull;
    return p;
  };
  unsigned* m_buf = (unsigned*)alloc((u64)NE * 64 * 4);   // 102.4 MB
  ushort_t* PQb  = (ushort_t*)alloc((u64)NA * DF * 2);
  float* sA      = (float*)alloc((u64)NA * DF * 4);
  ushort_t* WpB  = (ushort_t*)alloc(3 * 16384 * 2);
  ushort_t* WhB  = (ushort_t*)alloc(3 * 4096 * 2);
  ushort_t* WoB  = (ushort_t*)alloc(3 * 8192 * 2);
  // zero-init block (single memset)
  char* zbase    = ws + o;
  float* molr    = (float*)alloc((u64)NMOL * DF * 4);
  int* counts    = (int*)alloc((u64)NA * 4);
  int* cursor    = (int*)alloc((u64)NA * 4);
  int* mcnt      = (int*)alloc(NMOL * 4);
  int* mcur      = (int*)alloc(NMOL * 4);
  u64 zbytes     = (u64)((ws + o) - zbase);
  int* row_ptr   = (int*)alloc((u64)(NA + 1) * 4);
  int* mrow      = (int*)alloc((NMOL + 1) * 4);
  int* dst_s     = (int*)alloc((u64)NE * 4);
  int* src_s     = (int*)alloc((u64)NE * 4);
  int* mol_sorted = (int*)alloc((u64)NA * 4);
  int* scan_tmp  = (int*)alloc((u64)NA * 4);
  int* blk_sums  = (int*)alloc(64 * 4);
  (void)ws_size; (void)in_sizes; (void)n_in; (void)out_size;

  const int NSCAN = (NA + 1023) / 1024;  // 49

  hipMemsetAsync(zbase, 0, zbytes, stream);

  pack_weights<<<336, 256, 0, stream>>>(Win, Wh, Wout, WpB, WhB, WoB);
  count_edges<<<(NE + 255) / 256, 256, 0, stream>>>(dst, counts);
  scan_phase1<<<NSCAN, 1024, 0, stream>>>(counts, scan_tmp, blk_sums);
  scan_phase2<<<1, 64, 0, stream>>>(blk_sums, NSCAN);
  scan_phase3<<<NSCAN, 1024, 0, stream>>>(scan_tmp, blk_sums, row_ptr);
  fill_edges<<<(NE + 255) / 256, 256, 0, stream>>>(src, dst, row_ptr, cursor, dst_s, src_s);
  count_mols<<<(NA + 255) / 256, 256, 0, stream>>>(mol_ids, mcnt);
  scan_mols<<<1, NMOL, 0, stream>>>(mcnt, mrow);
  fill_mols<<<(NA + 255) / 256, 256, 0, stream>>>(mol_ids, mrow, mcur, mol_sorted);

  const float* scur = states;
  for (int t = 0; t < NSTEP; t++) {
    node_proj<<<(NA + 63) / 64, 256, 0, stream>>>(scur, WpB + t * 16384, PQb);
    edge_msg<<<(NE + 127) / 128, 256, 0, stream>>>(
        PQb, WhB + t * 4096, WoB + t * 8192,
        b_in + t * 64, b_h + t * 64, b_out + t * 128, dst_s, src_s, m_buf);
    agg_dst<<<(NA * 64 + 255) / 256, 256, 0, stream>>>(m_buf, row_ptr, sA);
    scur = sA;
  }
  agg_mol<<<(NA + 127) / 128, 128, 0, stream>>>(sA, mol_sorted, mol_ids, molr);
  final_mlp<<<NMOL, 64, 0, stream>>>(molr, fc1_w, fc1_b, fc2_w, fc2_b, out_w, out_b,
                                     (float*)d_out);
}